// Round 1
// baseline (1392.933 us; speedup 1.0000x reference)
//
#include <hip/hip_runtime.h>
#include <math.h>

#define N_NODES  100000
#define N_EDGES  3200000
#define N_GRAPHS 512
#define N_FEAT   128
#define DIM      10
#define OUT      16

// gptr[g] = first node index with batch >= g (batch is sorted). gptr[N_GRAPHS] = N_NODES.
__global__ void k_bounds(const int* __restrict__ batch, int* __restrict__ gptr) {
    int n = blockIdx.x * blockDim.x + threadIdx.x;
    if (n >= N_NODES) return;
    int bn = batch[n];
    int bp = (n == 0) ? -1 : batch[n - 1];
    for (int g = bp + 1; g <= bn; ++g) gptr[g] = n;
    if (n == N_NODES - 1) {
        for (int g = bn + 1; g <= N_GRAPHS; ++g) gptr[g] = N_NODES;
    }
}

// p[n][f] = sum_j x[n][j] * w1[j][f]   (128 -> 10), one wave per node
__global__ void k_proj1(const float* __restrict__ x, const float* __restrict__ w1,
                        float* __restrict__ p) {
    int wid  = (blockIdx.x * blockDim.x + threadIdx.x) >> 6;
    int lane = threadIdx.x & 63;
    if (wid >= N_NODES) return;
    float x1 = x[wid * N_FEAT + lane];
    float x2 = x[wid * N_FEAT + 64 + lane];
    float acc[DIM];
#pragma unroll
    for (int f = 0; f < DIM; ++f)
        acc[f] = x1 * w1[lane * DIM + f] + x2 * w1[(lane + 64) * DIM + f];
#pragma unroll
    for (int f = 0; f < DIM; ++f) {
        float v = acc[f];
        v += __shfl_xor(v, 32);
        v += __shfl_xor(v, 16);
        v += __shfl_xor(v, 8);
        v += __shfl_xor(v, 4);
        v += __shfl_xor(v, 2);
        v += __shfl_xor(v, 1);
        acc[f] = v;
    }
    if (lane == 0) {
#pragma unroll
        for (int f = 0; f < DIM; ++f) p[wid * DIM + f] = acc[f];
    }
}

// agg[dst][f] += p[src][f] over all edges; thread per (edge, feature)
__global__ void k_edges(const int* __restrict__ ei, const float* __restrict__ p,
                        float* __restrict__ agg) {
    int t = blockIdx.x * blockDim.x + threadIdx.x;
    if (t >= N_EDGES * DIM) return;
    int e = t / DIM;
    int f = t - e * DIM;
    int src = ei[e];
    int dst = ei[N_EDGES + e];
    atomicAdd(&agg[dst * DIM + f], p[src * DIM + f]);
}

// u = relu(p + agg + b1); h = relu(u@w2 + b2); pn = h @ w1_next. Re-zeros agg.
template <int HAS_NEXT>
__global__ void k_update(const float* __restrict__ p, float* __restrict__ agg,
                         const float* __restrict__ b1, const float* __restrict__ w2,
                         const float* __restrict__ b2, const float* __restrict__ w1n,
                         float* __restrict__ h, float* __restrict__ pn) {
    __shared__ float s_w2[DIM * DIM], s_w1n[DIM * DIM], s_b1[DIM], s_b2[DIM];
    int tid = threadIdx.x;
    if (tid < DIM * DIM) {
        s_w2[tid] = w2[tid];
        if (HAS_NEXT) s_w1n[tid] = w1n[tid];
    }
    if (tid < DIM) { s_b1[tid] = b1[tid]; s_b2[tid] = b2[tid]; }
    __syncthreads();
    int n = blockIdx.x * blockDim.x + tid;
    if (n >= N_NODES) return;

    float u[DIM];
#pragma unroll
    for (int f = 0; f < DIM; ++f) {
        float a = agg[n * DIM + f];
        u[f] = fmaxf(p[n * DIM + f] + a + s_b1[f], 0.f);
        agg[n * DIM + f] = 0.f;   // re-zero for next layer's atomics
    }
    float hv[DIM];
#pragma unroll
    for (int f = 0; f < DIM; ++f) {
        float v = s_b2[f];
#pragma unroll
        for (int j = 0; j < DIM; ++j) v += u[j] * s_w2[j * DIM + f];
        hv[f] = fmaxf(v, 0.f);
        h[n * DIM + f] = hv[f];
    }
    if (HAS_NEXT) {
#pragma unroll
        for (int f = 0; f < DIM; ++f) {
            float v = 0.f;
#pragma unroll
            for (int j = 0; j < DIM; ++j) v += hv[j] * s_w1n[j * DIM + f];
            pn[n * DIM + f] = v;
        }
    }
}

// per-graph sum of h over the graph's (contiguous, batch-sorted) node range
__global__ void k_pool(const float* __restrict__ h, const int* __restrict__ gptr,
                       float* __restrict__ pool) {
    int g = blockIdx.x;
    int s = gptr[g], e = gptr[g + 1];
    float acc[DIM];
#pragma unroll
    for (int f = 0; f < DIM; ++f) acc[f] = 0.f;
    for (int n = s + threadIdx.x; n < e; n += blockDim.x) {
#pragma unroll
        for (int f = 0; f < DIM; ++f) acc[f] += h[n * DIM + f];
    }
#pragma unroll
    for (int f = 0; f < DIM; ++f) {
        float v = acc[f];
        v += __shfl_xor(v, 32);
        v += __shfl_xor(v, 16);
        v += __shfl_xor(v, 8);
        v += __shfl_xor(v, 4);
        v += __shfl_xor(v, 2);
        v += __shfl_xor(v, 1);
        acc[f] = v;
    }
    __shared__ float s_red[4][DIM];
    int wave = threadIdx.x >> 6, lane = threadIdx.x & 63;
    if (lane == 0) {
#pragma unroll
        for (int f = 0; f < DIM; ++f) s_red[wave][f] = acc[f];
    }
    __syncthreads();
    if (threadIdx.x < DIM) {
        float v = s_red[0][threadIdx.x] + s_red[1][threadIdx.x] +
                  s_red[2][threadIdx.x] + s_red[3][threadIdx.x];
        pool[g * DIM + threadIdx.x] = v;
    }
}

// out[g][o] = tanh( sum_l (pool_l[g]/cnt_g) @ l_l[:,o] )
__global__ void k_out(const float* __restrict__ pool, const int* __restrict__ gptr,
                      const float* __restrict__ l1, const float* __restrict__ l2,
                      const float* __restrict__ l3, const float* __restrict__ l4,
                      const float* __restrict__ l5, float* __restrict__ out) {
    int t = blockIdx.x * blockDim.x + threadIdx.x;
    if (t >= N_GRAPHS * OUT) return;
    int g = t >> 4;
    int o = t & 15;
    float cnt = fmaxf((float)(gptr[g + 1] - gptr[g]), 1.f);
    const float* ls[5] = {l1, l2, l3, l4, l5};
    float acc = 0.f;
#pragma unroll
    for (int l = 0; l < 5; ++l) {
#pragma unroll
        for (int f = 0; f < DIM; ++f)
            acc += pool[(l * N_GRAPHS + g) * DIM + f] * ls[l][f * OUT + o];
    }
    out[t] = tanhf(acc / cnt);
}

extern "C" void kernel_launch(void* const* d_in, const int* in_sizes, int n_in,
                              void* d_out, int out_size, void* d_ws, size_t ws_size,
                              hipStream_t stream) {
    const float* x     = (const float*)d_in[0];
    const int*   ei    = (const int*)d_in[1];
    const int*   batch = (const int*)d_in[2];
    const float *w1[5], *b1[5], *w2[5], *b2[5], *lp[5];
    for (int l = 0; l < 5; ++l) {
        w1[l] = (const float*)d_in[3 + l * 4 + 0];
        b1[l] = (const float*)d_in[3 + l * 4 + 1];
        w2[l] = (const float*)d_in[3 + l * 4 + 2];
        b2[l] = (const float*)d_in[3 + l * 4 + 3];
        lp[l] = (const float*)d_in[23 + l];
    }
    float* out = (float*)d_out;

    float* pA   = (float*)d_ws;                       // N*DIM
    float* pB   = pA + N_NODES * DIM;                 // N*DIM
    float* agg  = pB + N_NODES * DIM;                 // N*DIM
    float* h    = agg + N_NODES * DIM;                // N*DIM
    float* pool = h + N_NODES * DIM;                  // 5*G*DIM
    int*   gptr = (int*)(pool + 5 * N_GRAPHS * DIM);  // G+1

    hipMemsetAsync(agg, 0, N_NODES * DIM * sizeof(float), stream);
    k_bounds<<<(N_NODES + 255) / 256, 256, 0, stream>>>(batch, gptr);
    k_proj1<<<(N_NODES * 64 + 255) / 256, 256, 0, stream>>>(x, w1[0], pA);

    float* pc  = pA;
    float* pnx = pB;
    for (int l = 0; l < 5; ++l) {
        k_edges<<<(N_EDGES * DIM + 255) / 256, 256, 0, stream>>>(ei, pc, agg);
        if (l < 4)
            k_update<1><<<(N_NODES + 255) / 256, 256, 0, stream>>>(
                pc, agg, b1[l], w2[l], b2[l], w1[l + 1], h, pnx);
        else
            k_update<0><<<(N_NODES + 255) / 256, 256, 0, stream>>>(
                pc, agg, b1[l], w2[l], b2[l], nullptr, h, nullptr);
        k_pool<<<N_GRAPHS, 256, 0, stream>>>(h, gptr, pool + l * N_GRAPHS * DIM);
        float* tmp = pc; pc = pnx; pnx = tmp;
    }
    k_out<<<(N_GRAPHS * OUT + 255) / 256, 256, 0, stream>>>(
        pool, gptr, lp[0], lp[1], lp[2], lp[3], lp[4], out);
}

// Round 2
// 785.579 us; speedup vs baseline: 1.7731x; 1.7731x over previous
//
#include <hip/hip_runtime.h>
#include <math.h>

#define N_NODES  100000
#define N_EDGES  3200000
#define N_GRAPHS 512
#define N_FEAT   128
#define DIM      10
#define PDIM     12      // padded row stride (floats) so rows are 16B-aligned
#define OUT      16
#define NBLK     ((N_NODES + 255) / 256)   // 391

// gptr[g] = first node index with batch >= g (batch sorted). gptr[N_GRAPHS] = N_NODES.
__global__ void k_bounds(const int* __restrict__ batch, int* __restrict__ gptr) {
    int n = blockIdx.x * blockDim.x + threadIdx.x;
    if (n >= N_NODES) return;
    int bn = batch[n];
    int bp = (n == 0) ? -1 : batch[n - 1];
    for (int g = bp + 1; g <= bn; ++g) gptr[g] = n;
    if (n == N_NODES - 1)
        for (int g = bn + 1; g <= N_GRAPHS; ++g) gptr[g] = N_NODES;
}

// p[n][f] = sum_j x[n][j] * w1[j][f]   (128 -> 10), one wave per node, padded out
__global__ void k_proj1(const float* __restrict__ x, const float* __restrict__ w1,
                        float* __restrict__ p) {
    int wid  = (blockIdx.x * blockDim.x + threadIdx.x) >> 6;
    int lane = threadIdx.x & 63;
    if (wid >= N_NODES) return;
    float x1 = x[wid * N_FEAT + lane];
    float x2 = x[wid * N_FEAT + 64 + lane];
    float acc[DIM];
#pragma unroll
    for (int f = 0; f < DIM; ++f)
        acc[f] = x1 * w1[lane * DIM + f] + x2 * w1[(lane + 64) * DIM + f];
#pragma unroll
    for (int f = 0; f < DIM; ++f) {
        float v = acc[f];
        v += __shfl_xor(v, 32); v += __shfl_xor(v, 16); v += __shfl_xor(v, 8);
        v += __shfl_xor(v, 4);  v += __shfl_xor(v, 2);  v += __shfl_xor(v, 1);
        acc[f] = v;
    }
    if (lane == 0) {
#pragma unroll
        for (int f = 0; f < DIM; ++f) p[wid * PDIM + f] = acc[f];
    }
}

// ---- CSR build (per call, deterministic work) ----
__global__ void k_degree(const int* __restrict__ ei, int* __restrict__ deg) {
    int e = blockIdx.x * blockDim.x + threadIdx.x;
    if (e >= N_EDGES) return;
    atomicAdd(&deg[ei[N_EDGES + e]], 1);
}

__global__ void k_bsum(const int* __restrict__ deg, int* __restrict__ bsum) {
    __shared__ int s[256];
    int i = blockIdx.x * 256 + threadIdx.x;
    s[threadIdx.x] = (i < N_NODES) ? deg[i] : 0;
    __syncthreads();
    for (int off = 128; off > 0; off >>= 1) {
        if (threadIdx.x < off) s[threadIdx.x] += s[threadIdx.x + off];
        __syncthreads();
    }
    if (threadIdx.x == 0) bsum[blockIdx.x] = s[0];
}

__global__ void k_bscan(int* __restrict__ bsum, int* __restrict__ rowp) {
    __shared__ int s[512];
    int tid = threadIdx.x;
    s[tid] = (tid < NBLK) ? bsum[tid] : 0;
    __syncthreads();
    for (int off = 1; off < 512; off <<= 1) {
        int v = (tid >= off) ? s[tid - off] : 0;
        __syncthreads();
        s[tid] += v;
        __syncthreads();
    }
    if (tid < NBLK) bsum[tid] = (tid == 0) ? 0 : s[tid - 1];  // exclusive block offsets
    if (tid == 511) rowp[N_NODES] = s[511];                    // total = N_EDGES
}

__global__ void k_scanw(const int* __restrict__ deg, const int* __restrict__ boff,
                        int* __restrict__ rowp) {
    __shared__ int s[256];
    int i = blockIdx.x * 256 + threadIdx.x;
    int d = (i < N_NODES) ? deg[i] : 0;
    s[threadIdx.x] = d;
    __syncthreads();
    for (int off = 1; off < 256; off <<= 1) {
        int v = (threadIdx.x >= off) ? s[threadIdx.x - off] : 0;
        __syncthreads();
        s[threadIdx.x] += v;
        __syncthreads();
    }
    if (i < N_NODES) rowp[i] = boff[blockIdx.x] + s[threadIdx.x] - d;
}

__global__ void k_scatter(const int* __restrict__ ei, const int* __restrict__ rowp,
                          int* __restrict__ cur, int* __restrict__ col) {
    int e = blockIdx.x * blockDim.x + threadIdx.x;
    if (e >= N_EDGES) return;
    int src = ei[e];
    int dst = ei[N_EDGES + e];
    int slot = rowp[dst] + atomicAdd(&cur[dst], 1);
    col[slot] = src;
}

// ---- fused gather + MLP update: u=relu(p_n + sum p_src + b1); h=relu(u@w2+b2); pn=h@w1n
template <int HAS_NEXT>
__global__ void k_layer(const float* __restrict__ p, const int* __restrict__ rowp,
                        const int* __restrict__ col,
                        const float* __restrict__ b1, const float* __restrict__ w2,
                        const float* __restrict__ b2, const float* __restrict__ w1n,
                        float* __restrict__ h, float* __restrict__ pn) {
    __shared__ float s_w2[DIM * DIM], s_w1n[DIM * DIM], s_b1[DIM], s_b2[DIM];
    int tid = threadIdx.x;
    if (tid < DIM * DIM) {
        s_w2[tid] = w2[tid];
        if (HAS_NEXT) s_w1n[tid] = w1n[tid];
    }
    if (tid < DIM) { s_b1[tid] = b1[tid]; s_b2[tid] = b2[tid]; }
    __syncthreads();
    int n = blockIdx.x * blockDim.x + tid;
    if (n >= N_NODES) return;

    float acc[DIM];
    {
        const float4* q = (const float4*)&p[n * PDIM];
        float4 a0 = q[0], a1 = q[1];
        float2 a2 = *(const float2*)&p[n * PDIM + 8];
        acc[0] = a0.x; acc[1] = a0.y; acc[2] = a0.z; acc[3] = a0.w;
        acc[4] = a1.x; acc[5] = a1.y; acc[6] = a1.z; acc[7] = a1.w;
        acc[8] = a2.x; acc[9] = a2.y;
    }
    int beg = rowp[n], end = rowp[n + 1];
    for (int j = beg; j < end; ++j) {
        int src = col[j];
        const float4* q = (const float4*)&p[src * PDIM];
        float4 b0 = q[0], b1v = q[1];
        float2 b2v = *(const float2*)&p[src * PDIM + 8];
        acc[0] += b0.x;  acc[1] += b0.y;  acc[2] += b0.z;  acc[3] += b0.w;
        acc[4] += b1v.x; acc[5] += b1v.y; acc[6] += b1v.z; acc[7] += b1v.w;
        acc[8] += b2v.x; acc[9] += b2v.y;
    }
    float u[DIM];
#pragma unroll
    for (int f = 0; f < DIM; ++f) u[f] = fmaxf(acc[f] + s_b1[f], 0.f);
    float hv[DIM];
#pragma unroll
    for (int f = 0; f < DIM; ++f) {
        float v = s_b2[f];
#pragma unroll
        for (int j = 0; j < DIM; ++j) v += u[j] * s_w2[j * DIM + f];
        hv[f] = fmaxf(v, 0.f);
        h[n * DIM + f] = hv[f];
    }
    if (HAS_NEXT) {
#pragma unroll
        for (int f = 0; f < DIM; ++f) {
            float v = 0.f;
#pragma unroll
            for (int j = 0; j < DIM; ++j) v += hv[j] * s_w1n[j * DIM + f];
            pn[n * PDIM + f] = v;
        }
    }
}

// per-graph sum of h over contiguous node range
__global__ void k_pool(const float* __restrict__ h, const int* __restrict__ gptr,
                       float* __restrict__ pool) {
    int g = blockIdx.x;
    int s = gptr[g], e = gptr[g + 1];
    float acc[DIM];
#pragma unroll
    for (int f = 0; f < DIM; ++f) acc[f] = 0.f;
    for (int n = s + threadIdx.x; n < e; n += blockDim.x) {
#pragma unroll
        for (int f = 0; f < DIM; ++f) acc[f] += h[n * DIM + f];
    }
#pragma unroll
    for (int f = 0; f < DIM; ++f) {
        float v = acc[f];
        v += __shfl_xor(v, 32); v += __shfl_xor(v, 16); v += __shfl_xor(v, 8);
        v += __shfl_xor(v, 4);  v += __shfl_xor(v, 2);  v += __shfl_xor(v, 1);
        acc[f] = v;
    }
    __shared__ float s_red[4][DIM];
    int wave = threadIdx.x >> 6, lane = threadIdx.x & 63;
    if (lane == 0) {
#pragma unroll
        for (int f = 0; f < DIM; ++f) s_red[wave][f] = acc[f];
    }
    __syncthreads();
    if (threadIdx.x < DIM) {
        pool[g * DIM + threadIdx.x] = s_red[0][threadIdx.x] + s_red[1][threadIdx.x] +
                                      s_red[2][threadIdx.x] + s_red[3][threadIdx.x];
    }
}

__global__ void k_out(const float* __restrict__ pool, const int* __restrict__ gptr,
                      const float* __restrict__ l1, const float* __restrict__ l2,
                      const float* __restrict__ l3, const float* __restrict__ l4,
                      const float* __restrict__ l5, float* __restrict__ out) {
    int t = blockIdx.x * blockDim.x + threadIdx.x;
    if (t >= N_GRAPHS * OUT) return;
    int g = t >> 4;
    int o = t & 15;
    float cnt = fmaxf((float)(gptr[g + 1] - gptr[g]), 1.f);
    const float* ls[5] = {l1, l2, l3, l4, l5};
    float acc = 0.f;
#pragma unroll
    for (int l = 0; l < 5; ++l)
#pragma unroll
        for (int f = 0; f < DIM; ++f)
            acc += pool[(l * N_GRAPHS + g) * DIM + f] * ls[l][f * OUT + o];
    out[t] = tanhf(acc / cnt);
}

extern "C" void kernel_launch(void* const* d_in, const int* in_sizes, int n_in,
                              void* d_out, int out_size, void* d_ws, size_t ws_size,
                              hipStream_t stream) {
    const float* x     = (const float*)d_in[0];
    const int*   ei    = (const int*)d_in[1];
    const int*   batch = (const int*)d_in[2];
    const float *w1[5], *b1[5], *w2[5], *b2[5], *lp[5];
    for (int l = 0; l < 5; ++l) {
        w1[l] = (const float*)d_in[3 + l * 4 + 0];
        b1[l] = (const float*)d_in[3 + l * 4 + 1];
        w2[l] = (const float*)d_in[3 + l * 4 + 2];
        b2[l] = (const float*)d_in[3 + l * 4 + 3];
        lp[l] = (const float*)d_in[23 + l];
    }
    float* out = (float*)d_out;

    // workspace layout (floats; every segment 16B-aligned)
    float* pA   = (float*)d_ws;                         // N*PDIM = 1,200,000
    float* pB   = pA + N_NODES * PDIM;                  // 1,200,000
    float* h    = pB + N_NODES * PDIM;                  // 1,000,000
    float* pool = h + N_NODES * DIM;                    // 5*G*DIM = 25,600
    int*   gptr = (int*)(pool + 5 * N_GRAPHS * DIM);    // 513
    int*   deg  = gptr + 516;                           // 100,000
    int*   cur  = deg + N_NODES;                        // 100,000
    int*   bsum = cur + N_NODES;                        // NBLK (391) -> pad 400
    int*   rowp = bsum + 400;                           // 100,001 -> pad 100,004
    int*   col  = rowp + 100004;                        // N_EDGES = 3,200,000
    // total ~ 27.4 MB

    hipMemsetAsync(deg, 0, N_NODES * sizeof(int), stream);
    hipMemsetAsync(cur, 0, N_NODES * sizeof(int), stream);

    k_bounds<<<NBLK, 256, 0, stream>>>(batch, gptr);
    k_proj1<<<(N_NODES * 64 + 255) / 256, 256, 0, stream>>>(x, w1[0], pA);

    // CSR build
    k_degree<<<(N_EDGES + 255) / 256, 256, 0, stream>>>(ei, deg);
    k_bsum<<<NBLK, 256, 0, stream>>>(deg, bsum);
    k_bscan<<<1, 512, 0, stream>>>(bsum, rowp);
    k_scanw<<<NBLK, 256, 0, stream>>>(deg, bsum, rowp);
    k_scatter<<<(N_EDGES + 255) / 256, 256, 0, stream>>>(ei, rowp, cur, col);

    float* pc  = pA;
    float* pnx = pB;
    for (int l = 0; l < 5; ++l) {
        if (l < 4)
            k_layer<1><<<NBLK, 256, 0, stream>>>(pc, rowp, col, b1[l], w2[l], b2[l],
                                                 w1[l + 1], h, pnx);
        else
            k_layer<0><<<NBLK, 256, 0, stream>>>(pc, rowp, col, b1[l], w2[l], b2[l],
                                                 nullptr, h, nullptr);
        k_pool<<<N_GRAPHS, 256, 0, stream>>>(h, gptr, pool + l * N_GRAPHS * DIM);
        float* tmp = pc; pc = pnx; pnx = tmp;
    }
    k_out<<<(N_GRAPHS * OUT + 255) / 256, 256, 0, stream>>>(
        pool, gptr, lp[0], lp[1], lp[2], lp[3], lp[4], out);
}